// Round 11
// baseline (195.600 us; speedup 1.0000x reference)
//
#include <hip/hip_runtime.h>
#include <hip/hip_bf16.h>

// ContralateralAttention, round 10: proj_ln at BK=32 -> 52KB LDS -> 3 blocks/CU.
// Tokens: t = b*4096 + y*64 + x (x in [0,64)), 32768 total.
// ws layout (MB), lifetime-packed:
//   Xbf   [  0, 16)   32768x256  bf16
//   wbf   [ 16, 17)   in_w | out_w | proj_w bf16
//   qkv   [ 17, 65)   32768x768  bf16   (dead after attn)
//   ctx   [ 65, 81)   32768x256  bf16

#define NTOK 32768

using bf16x8 = __attribute__((ext_vector_type(8))) short;
using f32x4  = __attribute__((ext_vector_type(4))) float;

__device__ __forceinline__ float b2f(short s) {
    unsigned u = ((unsigned)(unsigned short)s) << 16;
    union { unsigned u; float f; } c; c.u = u; return c.f;
}
__device__ __forceinline__ short f2b(float f) {
    __hip_bfloat16 h = __float2bfloat16(f);
    return *(short*)&h;
}
__device__ __forceinline__ void async_copy16(const void* g, void* l) {
    __builtin_amdgcn_global_load_lds(
        (const __attribute__((address_space(1))) unsigned int*)g,
        (__attribute__((address_space(3))) unsigned int*)l, 16, 0, 0);
}

// ---------------- prep: feat transpose+cast AND weight casts, one kernel ----------------
__global__ __launch_bounds__(256) void prep_kernel(const float* __restrict__ feat,
                                                   const float* __restrict__ in_w,
                                                   const float* __restrict__ out_w,
                                                   const float* __restrict__ proj_w,
                                                   __hip_bfloat16* __restrict__ X,
                                                   __hip_bfloat16* __restrict__ wbf) {
    const int bid = blockIdx.x;
    const int tid = threadIdx.x;
    if (bid < 8192) {
        __shared__ float tile[32][33];
        const int sp0 = (bid & 127) * 32;
        const int c0  = ((bid >> 7) & 7) * 32;
        const int b   = bid >> 10;
        const int col = tid & 31, rowg = tid >> 5;
        #pragma unroll
        for (int u = 0; u < 4; ++u) {
            int cl = rowg + u * 8;
            tile[cl][col] = feat[((size_t)(b * 256 + c0 + cl) << 12) + sp0 + col];
        }
        __syncthreads();
        #pragma unroll
        for (int u = 0; u < 4; ++u) {
            int spl = rowg + u * 8;
            X[(size_t)(b * 4096 + sp0 + spl) * 256 + c0 + col] = __float2bfloat16(tile[col][spl]);
        }
    } else {
        const int i = (bid - 8192) * 256 + tid;
        if (i < 196608) wbf[i] = __float2bfloat16(in_w[i]);
        if (i < 65536)  wbf[196608 + i] = __float2bfloat16(out_w[i]);
        if (i < 262144) wbf[262144 + i] = __float2bfloat16(proj_w[i]);
    }
}

// ---------------- MFMA GEMM (qkv): 256 thr, M=128 x N=128, BK=64, DMA staging ----------------
template <int KDIM, bool OUT_BF16>
__global__ __launch_bounds__(256) void mfma_gemm(const __hip_bfloat16* __restrict__ A,
                                                 const __hip_bfloat16* __restrict__ W,
                                                 const float* __restrict__ bias,
                                                 void* __restrict__ C, int Ntot) {
    __shared__ __align__(16) short As[128 * 64];
    __shared__ __align__(16) short Bs[128 * 64];
    const int tid = threadIdx.x;
    const int m0 = blockIdx.x * 128;
    const int n0 = blockIdx.y * 128;
    const int wave = tid >> 6, lane = tid & 63;
    const int wm = (wave >> 1) * 64;
    const int wn = (wave & 1) * 64;
    const int fm = lane & 15;
    const int fq = lane >> 4;

    f32x4 acc[4][4] = {};

    for (int k0 = 0; k0 < KDIM; k0 += 64) {
        #pragma unroll
        for (int v = 0; v < 4; ++v) {
            const int qb = v * 256 + wave * 64;
            const int q = qb + lane;
            const int r = q >> 3;
            const int cs = (q & 7) ^ (r & 7);
            async_copy16(A + (size_t)(m0 + r) * KDIM + k0 + cs * 8, &As[qb * 8]);
            async_copy16(W + (size_t)(n0 + r) * KDIM + k0 + cs * 8, &Bs[qb * 8]);
        }
        __syncthreads();
        #pragma unroll
        for (int kk = 0; kk < 2; ++kk) {
            bf16x8 af[4], bw[4];
            #pragma unroll
            for (int i = 0; i < 4; ++i) {
                const int row = wm + i * 16 + fm;
                af[i] = *(const bf16x8*)(&As[row * 64 + (((fq + kk * 4) ^ (fm & 7)) * 8)]);
            }
            #pragma unroll
            for (int j = 0; j < 4; ++j) {
                const int row = wn + j * 16 + fm;
                bw[j] = *(const bf16x8*)(&Bs[row * 64 + (((fq + kk * 4) ^ (fm & 7)) * 8)]);
            }
            #pragma unroll
            for (int i = 0; i < 4; ++i)
                #pragma unroll
                for (int j = 0; j < 4; ++j)
                    acc[i][j] = __builtin_amdgcn_mfma_f32_16x16x32_bf16(af[i], bw[j], acc[i][j], 0, 0, 0);
        }
        __syncthreads();
    }
    #pragma unroll
    for (int j = 0; j < 4; ++j) {
        const int col = n0 + wn + j * 16 + fm;
        const float bv = bias[col];
        #pragma unroll
        for (int i = 0; i < 4; ++i) {
            #pragma unroll
            for (int r = 0; r < 4; ++r) {
                const int row = m0 + wm + i * 16 + fq * 4 + r;
                const float v = acc[i][j][r] + bv;
                if (OUT_BF16)
                    ((__hip_bfloat16*)C)[(size_t)row * Ntot + col] = __float2bfloat16(v);
                else
                    ((float*)C)[(size_t)row * Ntot + col] = v;
            }
        }
    }
}

// ---------------- sparse attention: one wave/token, 4 heads (pairs), coalesced loads ----------------
#define P0DY ((2u)|(2u<<3)|(2u<<6)|(2u<<9)|(2u<<12)|(1u<<15)|(1u<<18)|(1u<<21))
#define P0DX ((2u)|(1u<<3)|(3u<<6)|(0u<<9)|(4u<<12)|(2u<<15)|(1u<<18)|(3u<<21))
#define P1DY ((3u)|(3u<<3)|(3u<<6)|(0u<<9)|(4u<<12)|(2u<<15)|(2u<<18)|(2u<<21))
#define P1DX ((2u)|(1u<<3)|(3u<<6)|(2u<<9)|(2u<<12)|(2u<<15)|(2u<<18)|(2u<<21))

__global__ __launch_bounds__(256) void attn_kernel(const __hip_bfloat16* __restrict__ qkv,
                                                   __hip_bfloat16* __restrict__ ctx) {
    const int t = blockIdx.x * 4 + (threadIdx.x >> 6);
    const int lane = threadIdx.x & 63;
    const int n  = lane >> 3;
    const int cg = lane & 7;
    const int x6 = t & 63;
    const int yq = (t >> 6) & 63;
    const int b  = t >> 12;
    const int side = x6 >> 5;
    const int x = x6 & 31;

    bool valid[2];
    size_t kb[2];
    #pragma unroll
    for (int p = 0; p < 2; ++p) {
        const unsigned dyp = p ? P1DY : P0DY;
        const unsigned dxp = p ? P1DX : P0DX;
        const int sh = 3 * n;
        const int dy = (int)((dyp >> sh) & 7) - 2;
        const int dx = (int)((dxp >> sh) & 7) - 2;
        const int yy = yq + dy, xx = x + dx;
        valid[p] = (p == 0 || n < 5) && yy >= 0 && yy < 64 && xx >= 0 && xx < 32;
        const int xm = side ? (31 - xx) : (63 - xx);
        int tm = (b << 12) + (yy << 6) + xm;
        if (!valid[p]) tm = t;
        kb[p] = (size_t)tm * 768 + 256 + cg * 8;
    }
    const size_t qb = (size_t)t * 768 + cg * 8;
    const size_t ob = (size_t)t * 256;

    #pragma unroll
    for (int hp = 0; hp < 2; ++hp) {
        bf16x8 q8[2], k8[2][2], v8[2][2];
        #pragma unroll
        for (int hh = 0; hh < 2; ++hh) {
            const int h = hp * 2 + hh;
            q8[hh] = *(const bf16x8*)(qkv + qb + h * 64);
            #pragma unroll
            for (int p = 0; p < 2; ++p) {
                k8[hh][p] = *(const bf16x8*)(qkv + kb[p] + h * 64);
                v8[hh][p] = *(const bf16x8*)(qkv + kb[p] + h * 64 + 256);
            }
        }
        #pragma unroll
        for (int hh = 0; hh < 2; ++hh) {
            float sc[2];
            #pragma unroll
            for (int p = 0; p < 2; ++p) {
                float s = 0.f;
                #pragma unroll
                for (int j = 0; j < 8; ++j) s += b2f(q8[hh][j]) * b2f(k8[hh][p][j]);
                s += __shfl_xor(s, 1, 64);
                s += __shfl_xor(s, 2, 64);
                s += __shfl_xor(s, 4, 64);
                sc[p] = valid[p] ? s * 0.125f : -1e30f;
            }
            const float p0 = __expf(sc[0]);
            const float p1 = __expf(sc[1]);
            float l = p0 + p1;
            l += __shfl_xor(l, 8, 64);
            l += __shfl_xor(l, 16, 64);
            l += __shfl_xor(l, 32, 64);

            float o[8];
            #pragma unroll
            for (int j = 0; j < 8; ++j)
                o[j] = p0 * b2f(v8[hh][0][j]) + p1 * b2f(v8[hh][1][j]);
            float r4[4];
            #pragma unroll
            for (int i = 0; i < 4; ++i) {
                const float a = o[2 * i], bb = o[2 * i + 1];
                const float mine = (n & 1) ? bb : a;
                const float theirs = (n & 1) ? a : bb;
                r4[i] = mine + __shfl_xor(theirs, 8, 64);
            }
            float r2[2];
            #pragma unroll
            for (int i = 0; i < 2; ++i) {
                const float a = r4[2 * i], bb = r4[2 * i + 1];
                const float mine = (n & 2) ? bb : a;
                const float theirs = (n & 2) ? a : bb;
                r2[i] = mine + __shfl_xor(theirs, 16, 64);
            }
            float ov;
            {
                const float a = r2[0], bb = r2[1];
                const float mine = (n & 4) ? bb : a;
                const float theirs = (n & 4) ? a : bb;
                ov = mine + __shfl_xor(theirs, 32, 64);
            }
            const float rl = __builtin_amdgcn_rcpf(l);
            ctx[ob + (hp * 2 + hh) * 64 + cg * 8 + n] = __float2bfloat16(ov * rl);
        }
    }
}

// ---------------- fused: ctx2 = ctx@out_w^T+out_b (in LDS), then proj+LN+ReLU+store ----------------
// 256 thr, M=64 tokens, BK=32 both phases. LDS 52KB -> 3 blocks/CU.
// smem shorts: c2s [0,16384) | As [16384,18432) | Bs [18432,26624); ys overlays [0,17024).
__global__ __launch_bounds__(256) void proj_ln_fused(const __hip_bfloat16* __restrict__ X,
                                                     const __hip_bfloat16* __restrict__ CTX,
                                                     const __hip_bfloat16* __restrict__ W2,
                                                     const float* __restrict__ out_b,
                                                     const __hip_bfloat16* __restrict__ W,
                                                     const float* __restrict__ bias,
                                                     const float* __restrict__ ln_g,
                                                     const float* __restrict__ ln_b,
                                                     float* __restrict__ out) {
    __shared__ __align__(16) short smem[26624];   // 52 KB
    __shared__ float mu_s[64], inv_s[64];
    short* c2s = smem;            // 64 x 256 (32 KB), persists through phase B
    short* As  = smem + 16384;    // 64 x 32 staging (4 KB)
    short* Bs  = smem + 18432;    // 256 x 32 staging (16 KB)
    const int tid = threadIdx.x;
    const int m0 = blockIdx.x * 64;
    const int b = m0 >> 12, sp0 = m0 & 4095;
    const int wave = tid >> 6, lane = tid & 63;
    const int wn = wave * 64;
    const int fm = lane & 15;
    const int fq = lane >> 4;
    const int csw = (fq ^ (fm & 3)) * 8;   // BK=32 frag chunk offset (shorts)

    // ---- phase A: ctx2 tile (K=256, BK=32) ----
    {
        f32x4 acc2[4][4] = {};
        for (int k0 = 0; k0 < 256; k0 += 32) {
            {   // ctx: 256 chunks, 1 round
                const int q = tid;
                const int r = q >> 2;
                const int cs = (q & 3) ^ (r & 3);
                async_copy16(CTX + (size_t)(m0 + r) * 256 + k0 + cs * 8, &As[wave * 64 * 8]);
            }
            #pragma unroll
            for (int v = 0; v < 4; ++v) {   // out_w: 1024 chunks, 4 rounds
                const int qbu = v * 256 + wave * 64;
                const int q = qbu + lane;
                const int r = q >> 2;
                const int cs = (q & 3) ^ (r & 3);
                async_copy16(W2 + (size_t)r * 256 + k0 + cs * 8, &Bs[qbu * 8]);
            }
            __syncthreads();
            bf16x8 af[4], bw[4];
            #pragma unroll
            for (int i = 0; i < 4; ++i)
                af[i] = *(const bf16x8*)(&As[(i * 16 + fm) * 32 + csw]);
            #pragma unroll
            for (int j = 0; j < 4; ++j)
                bw[j] = *(const bf16x8*)(&Bs[(wn + j * 16 + fm) * 32 + csw]);
            #pragma unroll
            for (int i = 0; i < 4; ++i)
                #pragma unroll
                for (int j = 0; j < 4; ++j)
                    acc2[i][j] = __builtin_amdgcn_mfma_f32_16x16x32_bf16(af[i], bw[j], acc2[i][j], 0, 0, 0);
            __syncthreads();
        }
        // park ctx2 in c2s (bf16), chunk j of row r at slot (j&24)|((j&7)^(r&7))
        #pragma unroll
        for (int j = 0; j < 4; ++j) {
            const int col = wn + j * 16 + fm;
            const float bv = out_b[col];
            const int jch = col >> 3, cl = col & 7;
            #pragma unroll
            for (int i = 0; i < 4; ++i)
                #pragma unroll
                for (int rr = 0; rr < 4; ++rr) {
                    const int row = i * 16 + fq * 4 + rr;
                    const int slot = (jch & 24) | ((jch & 7) ^ (row & 7));
                    c2s[row * 256 + slot * 8 + cl] = f2b(acc2[i][j][rr] + bv);
                }
        }
    }
    __syncthreads();

    // ---- phase B: proj GEMM over K=1024 groups [q | c2 | |q-c2| | q*c2], BK=32 ----
    f32x4 acc[4][4] = {};
    for (int k0 = 0; k0 < 1024; k0 += 32) {
        const int g = k0 >> 8;
        const int cb = k0 & 255;
        #pragma unroll
        for (int v = 0; v < 4; ++v) {       // proj_w: 1024 chunks, 4 rounds
            const int qbu = v * 256 + wave * 64;
            const int q = qbu + lane;
            const int r = q >> 2;
            const int cs = (q & 3) ^ (r & 3);
            async_copy16(W + (size_t)r * 1024 + k0 + cs * 8, &Bs[qbu * 8]);
        }
        if (g == 0) {
            const int q = tid;
            const int r = q >> 2;
            const int cs = (q & 3) ^ (r & 3);
            async_copy16(X + (size_t)(m0 + r) * 256 + cb + cs * 8, &As[wave * 64 * 8]);
        } else if (g >= 2) {
            const int q = tid;
            const int r = q >> 2;
            const int cs = (q & 3) ^ (r & 3);
            int4 qraw = *(const int4*)(X + (size_t)(m0 + r) * 256 + cb + cs * 8);
            const int jch = (cb >> 3) + cs;
            const int slot = (jch & 24) | ((jch & 7) ^ (r & 7));
            int4 craw = *(const int4*)(&c2s[r * 256 + slot * 8]);
            const short* qs = (const short*)&qraw;
            const short* cw = (const short*)&craw;
            short tmp[8];
            #pragma unroll
            for (int j = 0; j < 8; ++j) {
                const float qv = b2f(qs[j]), cv = b2f(cw[j]);
                tmp[j] = f2b(g == 2 ? fabsf(qv - cv) : qv * cv);
            }
            *(int4*)(&As[q * 8]) = *(int4*)tmp;
        }
        // g == 1: no A staging — frags read straight from c2s
        __syncthreads();
        bf16x8 af[4], bw[4];
        if (g == 1) {
            #pragma unroll
            for (int i = 0; i < 4; ++i) {
                const int row = i * 16 + fm;
                const int jch = (cb >> 3) + fq;
                const int slot = (jch & 24) | ((jch & 7) ^ (row & 7));
                af[i] = *(const bf16x8*)(&c2s[row * 256 + slot * 8]);
            }
        } else {
            #pragma unroll
            for (int i = 0; i < 4; ++i)
                af[i] = *(const bf16x8*)(&As[(i * 16 + fm) * 32 + csw]);
        }
        #pragma unroll
        for (int j = 0; j < 4; ++j)
            bw[j] = *(const bf16x8*)(&Bs[(wn + j * 16 + fm) * 32 + csw]);
        #pragma unroll
        for (int i = 0; i < 4; ++i)
            #pragma unroll
            for (int j = 0; j < 4; ++j)
                acc[i][j] = __builtin_amdgcn_mfma_f32_16x16x32_bf16(af[i], bw[j], acc[i][j], 0, 0, 0);
        __syncthreads();
    }
    // ---- epilogue: ys (bf16, stride 266) overlays c2s/As (both dead); LN; ReLU; store ----
    short* ys = smem;
    #pragma unroll
    for (int j = 0; j < 4; ++j) {
        const int col = wn + j * 16 + fm;
        const float bv = bias[col];
        #pragma unroll
        for (int i = 0; i < 4; ++i)
            #pragma unroll
            for (int r = 0; r < 4; ++r)
                ys[(i * 16 + fq * 4 + r) * 266 + col] = f2b(acc[i][j][r] + bv);
    }
    __syncthreads();
    {
        const int tt = tid >> 2, seg = tid & 3;
        float s = 0.f, ss = 0.f;
        #pragma unroll
        for (int j = 0; j < 64; ++j) {
            const float v = b2f(ys[tt * 266 + seg * 64 + j]);
            s += v; ss += v * v;
        }
        s += __shfl_xor(s, 1, 64);  ss += __shfl_xor(ss, 1, 64);
        s += __shfl_xor(s, 2, 64);  ss += __shfl_xor(ss, 2, 64);
        if (seg == 0) {
            const float mu = s * (1.f / 256.f);
            const float var = ss * (1.f / 256.f) - mu * mu;
            mu_s[tt] = mu;
            inv_s[tt] = rsqrtf(var + 1e-5f);
        }
    }
    __syncthreads();
    {
        const int tl = tid & 63;
        const int j0 = tid >> 6;
        const float mu = mu_s[tl], inv = inv_s[tl];
        #pragma unroll
        for (int u = 0; u < 64; ++u) {
            const int j = j0 * 64 + u;
            const float v = (b2f(ys[tl * 266 + j]) - mu) * inv * ln_g[j] + ln_b[j];
            out[((size_t)(b * 256 + j) << 12) + sp0 + tl] = fmaxf(v, 0.f);
        }
    }
}

extern "C" void kernel_launch(void* const* d_in, const int* in_sizes, int n_in,
                              void* d_out, int out_size, void* d_ws, size_t ws_size,
                              hipStream_t stream) {
    (void)in_sizes; (void)n_in; (void)out_size; (void)ws_size;
    const float* feat   = (const float*)d_in[0];
    const float* in_w   = (const float*)d_in[1];
    const float* in_b   = (const float*)d_in[2];
    const float* out_w  = (const float*)d_in[3];
    const float* out_b  = (const float*)d_in[4];
    const float* proj_w = (const float*)d_in[5];
    const float* proj_b = (const float*)d_in[6];
    const float* ln_g   = (const float*)d_in[7];
    const float* ln_b   = (const float*)d_in[8];
    float* out = (float*)d_out;

    char* ws = (char*)d_ws;
    __hip_bfloat16* Xbf  = (__hip_bfloat16*)(ws);
    __hip_bfloat16* wbf  = (__hip_bfloat16*)(ws + (size_t)(16) * (1 << 20));
    __hip_bfloat16* qkv  = (__hip_bfloat16*)(ws + (size_t)(17) * (1 << 20));
    __hip_bfloat16* ctx  = (__hip_bfloat16*)(ws + (size_t)(65) * (1 << 20));
    __hip_bfloat16* in_wbf   = wbf;
    __hip_bfloat16* out_wbf  = wbf + 196608;
    __hip_bfloat16* proj_wbf = wbf + 262144;

    prep_kernel   <<<9216, 256, 0, stream>>>(feat, in_w, out_w, proj_w, Xbf, wbf);
    mfma_gemm<256, true><<<dim3(256, 6), 256, 0, stream>>>(Xbf, in_wbf, in_b, qkv, 768);
    attn_kernel   <<<NTOK / 4, 256, 0, stream>>>(qkv, ctx);
    proj_ln_fused <<<NTOK / 64, 256, 0, stream>>>(Xbf, ctx, out_wbf, out_b,
                                                  proj_wbf, proj_b, ln_g, ln_b, out);
}

// Round 12
// 186.389 us; speedup vs baseline: 1.0494x; 1.0494x over previous
//
#include <hip/hip_runtime.h>
#include <hip/hip_bf16.h>

// ContralateralAttention, round 11: proj_ln back to BK=64 (r10's BK=32 regressed:
// conflicts x4, occupancy flat) but with 512 threads / 8 N-split waves per block
// -> 16 waves/CU at the same 72KB LDS.
// ws layout (MB): Xbf [0,16) | wbf [16,17) | qkv [17,65) | ctx [65,81)

#define NTOK 32768

using bf16x8 = __attribute__((ext_vector_type(8))) short;
using f32x4  = __attribute__((ext_vector_type(4))) float;

__device__ __forceinline__ float b2f(short s) {
    unsigned u = ((unsigned)(unsigned short)s) << 16;
    union { unsigned u; float f; } c; c.u = u; return c.f;
}
__device__ __forceinline__ short f2b(float f) {
    __hip_bfloat16 h = __float2bfloat16(f);
    return *(short*)&h;
}
__device__ __forceinline__ void async_copy16(const void* g, void* l) {
    __builtin_amdgcn_global_load_lds(
        (const __attribute__((address_space(1))) unsigned int*)g,
        (__attribute__((address_space(3))) unsigned int*)l, 16, 0, 0);
}

// ---------------- prep: feat transpose+cast AND weight casts ----------------
__global__ __launch_bounds__(256) void prep_kernel(const float* __restrict__ feat,
                                                   const float* __restrict__ in_w,
                                                   const float* __restrict__ out_w,
                                                   const float* __restrict__ proj_w,
                                                   __hip_bfloat16* __restrict__ X,
                                                   __hip_bfloat16* __restrict__ wbf) {
    const int bid = blockIdx.x;
    const int tid = threadIdx.x;
    if (bid < 8192) {
        __shared__ float tile[32][33];
        const int sp0 = (bid & 127) * 32;
        const int c0  = ((bid >> 7) & 7) * 32;
        const int b   = bid >> 10;
        const int col = tid & 31, rowg = tid >> 5;
        #pragma unroll
        for (int u = 0; u < 4; ++u) {
            int cl = rowg + u * 8;
            tile[cl][col] = feat[((size_t)(b * 256 + c0 + cl) << 12) + sp0 + col];
        }
        __syncthreads();
        #pragma unroll
        for (int u = 0; u < 4; ++u) {
            int spl = rowg + u * 8;
            X[(size_t)(b * 4096 + sp0 + spl) * 256 + c0 + col] = __float2bfloat16(tile[col][spl]);
        }
    } else {
        const int i = (bid - 8192) * 256 + tid;
        if (i < 196608) wbf[i] = __float2bfloat16(in_w[i]);
        if (i < 65536)  wbf[196608 + i] = __float2bfloat16(out_w[i]);
        if (i < 262144) wbf[262144 + i] = __float2bfloat16(proj_w[i]);
    }
}

// ---------------- MFMA GEMM (qkv): 256 thr, M=128 x N=128, BK=64, DMA staging ----------------
template <int KDIM, bool OUT_BF16>
__global__ __launch_bounds__(256) void mfma_gemm(const __hip_bfloat16* __restrict__ A,
                                                 const __hip_bfloat16* __restrict__ W,
                                                 const float* __restrict__ bias,
                                                 void* __restrict__ C, int Ntot) {
    __shared__ __align__(16) short As[128 * 64];
    __shared__ __align__(16) short Bs[128 * 64];
    const int tid = threadIdx.x;
    const int m0 = blockIdx.x * 128;
    const int n0 = blockIdx.y * 128;
    const int wave = tid >> 6, lane = tid & 63;
    const int wm = (wave >> 1) * 64;
    const int wn = (wave & 1) * 64;
    const int fm = lane & 15;
    const int fq = lane >> 4;

    f32x4 acc[4][4] = {};

    for (int k0 = 0; k0 < KDIM; k0 += 64) {
        #pragma unroll
        for (int v = 0; v < 4; ++v) {
            const int qb = v * 256 + wave * 64;
            const int q = qb + lane;
            const int r = q >> 3;
            const int cs = (q & 7) ^ (r & 7);
            async_copy16(A + (size_t)(m0 + r) * KDIM + k0 + cs * 8, &As[qb * 8]);
            async_copy16(W + (size_t)(n0 + r) * KDIM + k0 + cs * 8, &Bs[qb * 8]);
        }
        __syncthreads();
        #pragma unroll
        for (int kk = 0; kk < 2; ++kk) {
            bf16x8 af[4], bw[4];
            #pragma unroll
            for (int i = 0; i < 4; ++i) {
                const int row = wm + i * 16 + fm;
                af[i] = *(const bf16x8*)(&As[row * 64 + (((fq + kk * 4) ^ (fm & 7)) * 8)]);
            }
            #pragma unroll
            for (int j = 0; j < 4; ++j) {
                const int row = wn + j * 16 + fm;
                bw[j] = *(const bf16x8*)(&Bs[row * 64 + (((fq + kk * 4) ^ (fm & 7)) * 8)]);
            }
            #pragma unroll
            for (int i = 0; i < 4; ++i)
                #pragma unroll
                for (int j = 0; j < 4; ++j)
                    acc[i][j] = __builtin_amdgcn_mfma_f32_16x16x32_bf16(af[i], bw[j], acc[i][j], 0, 0, 0);
        }
        __syncthreads();
    }
    #pragma unroll
    for (int j = 0; j < 4; ++j) {
        const int col = n0 + wn + j * 16 + fm;
        const float bv = bias[col];
        #pragma unroll
        for (int i = 0; i < 4; ++i) {
            #pragma unroll
            for (int r = 0; r < 4; ++r) {
                const int row = m0 + wm + i * 16 + fq * 4 + r;
                const float v = acc[i][j][r] + bv;
                if (OUT_BF16)
                    ((__hip_bfloat16*)C)[(size_t)row * Ntot + col] = __float2bfloat16(v);
                else
                    ((float*)C)[(size_t)row * Ntot + col] = v;
            }
        }
    }
}

// ---------------- sparse attention (r7 form, validated) ----------------
#define P0DY ((2u)|(2u<<3)|(2u<<6)|(2u<<9)|(2u<<12)|(1u<<15)|(1u<<18)|(1u<<21))
#define P0DX ((2u)|(1u<<3)|(3u<<6)|(0u<<9)|(4u<<12)|(2u<<15)|(1u<<18)|(3u<<21))
#define P1DY ((3u)|(3u<<3)|(3u<<6)|(0u<<9)|(4u<<12)|(2u<<15)|(2u<<18)|(2u<<21))
#define P1DX ((2u)|(1u<<3)|(3u<<6)|(2u<<9)|(2u<<12)|(2u<<15)|(2u<<18)|(2u<<21))

__global__ __launch_bounds__(256) void attn_kernel(const __hip_bfloat16* __restrict__ qkv,
                                                   __hip_bfloat16* __restrict__ ctx) {
    const int t = blockIdx.x * 4 + (threadIdx.x >> 6);
    const int lane = threadIdx.x & 63;
    const int n  = lane >> 3;
    const int cg = lane & 7;
    const int x6 = t & 63;
    const int yq = (t >> 6) & 63;
    const int b  = t >> 12;
    const int side = x6 >> 5;
    const int x = x6 & 31;

    bool valid[2];
    size_t kb[2];
    #pragma unroll
    for (int p = 0; p < 2; ++p) {
        const unsigned dyp = p ? P1DY : P0DY;
        const unsigned dxp = p ? P1DX : P0DX;
        const int sh = 3 * n;
        const int dy = (int)((dyp >> sh) & 7) - 2;
        const int dx = (int)((dxp >> sh) & 7) - 2;
        const int yy = yq + dy, xx = x + dx;
        valid[p] = (p == 0 || n < 5) && yy >= 0 && yy < 64 && xx >= 0 && xx < 32;
        const int xm = side ? (31 - xx) : (63 - xx);
        int tm = (b << 12) + (yy << 6) + xm;
        if (!valid[p]) tm = t;
        kb[p] = (size_t)tm * 768 + 256 + cg * 8;
    }
    const size_t qb = (size_t)t * 768 + cg * 8;
    const size_t ob = (size_t)t * 256;

    #pragma unroll
    for (int hp = 0; hp < 2; ++hp) {
        bf16x8 q8[2], k8[2][2], v8[2][2];
        #pragma unroll
        for (int hh = 0; hh < 2; ++hh) {
            const int h = hp * 2 + hh;
            q8[hh] = *(const bf16x8*)(qkv + qb + h * 64);
            #pragma unroll
            for (int p = 0; p < 2; ++p) {
                k8[hh][p] = *(const bf16x8*)(qkv + kb[p] + h * 64);
                v8[hh][p] = *(const bf16x8*)(qkv + kb[p] + h * 64 + 256);
            }
        }
        #pragma unroll
        for (int hh = 0; hh < 2; ++hh) {
            float sc[2];
            #pragma unroll
            for (int p = 0; p < 2; ++p) {
                float s = 0.f;
                #pragma unroll
                for (int j = 0; j < 8; ++j) s += b2f(q8[hh][j]) * b2f(k8[hh][p][j]);
                s += __shfl_xor(s, 1, 64);
                s += __shfl_xor(s, 2, 64);
                s += __shfl_xor(s, 4, 64);
                sc[p] = valid[p] ? s * 0.125f : -1e30f;
            }
            const float p0 = __expf(sc[0]);
            const float p1 = __expf(sc[1]);
            float l = p0 + p1;
            l += __shfl_xor(l, 8, 64);
            l += __shfl_xor(l, 16, 64);
            l += __shfl_xor(l, 32, 64);

            float o[8];
            #pragma unroll
            for (int j = 0; j < 8; ++j)
                o[j] = p0 * b2f(v8[hh][0][j]) + p1 * b2f(v8[hh][1][j]);
            float r4[4];
            #pragma unroll
            for (int i = 0; i < 4; ++i) {
                const float a = o[2 * i], bb = o[2 * i + 1];
                const float mine = (n & 1) ? bb : a;
                const float theirs = (n & 1) ? a : bb;
                r4[i] = mine + __shfl_xor(theirs, 8, 64);
            }
            float r2[2];
            #pragma unroll
            for (int i = 0; i < 2; ++i) {
                const float a = r4[2 * i], bb = r4[2 * i + 1];
                const float mine = (n & 2) ? bb : a;
                const float theirs = (n & 2) ? a : bb;
                r2[i] = mine + __shfl_xor(theirs, 16, 64);
            }
            float ov;
            {
                const float a = r2[0], bb = r2[1];
                const float mine = (n & 4) ? bb : a;
                const float theirs = (n & 4) ? a : bb;
                ov = mine + __shfl_xor(theirs, 32, 64);
            }
            const float rl = __builtin_amdgcn_rcpf(l);
            ctx[ob + (hp * 2 + hh) * 64 + cg * 8 + n] = __float2bfloat16(ov * rl);
        }
    }
}

// ---------------- fused outproj + proj + LN, 512 threads, M=64, BK=64 ----------------
// 8 waves, wave n-strip = 32 (2 j-tiles). LDS 72KB -> 2 blocks/CU = 16 waves/CU.
// smem shorts: c2s [0,16384) | As [16384,20480) | Bs [20480,36864); ys overlays [0,17024).
__global__ __launch_bounds__(512) void proj_ln_fused(const __hip_bfloat16* __restrict__ X,
                                                     const __hip_bfloat16* __restrict__ CTX,
                                                     const __hip_bfloat16* __restrict__ W2,
                                                     const float* __restrict__ out_b,
                                                     const __hip_bfloat16* __restrict__ W,
                                                     const float* __restrict__ bias,
                                                     const float* __restrict__ ln_g,
                                                     const float* __restrict__ ln_b,
                                                     float* __restrict__ out) {
    __shared__ __align__(16) short smem[36864];   // 72 KB
    __shared__ float mu_s[64], inv_s[64];
    short* c2s = smem;            // 64 x 256 (32 KB), persists through phase B
    short* As  = smem + 16384;    // 64 x 64 staging (8 KB)
    short* Bs  = smem + 20480;    // 256 x 64 staging (32 KB)
    const int tid = threadIdx.x;
    const int m0 = blockIdx.x * 64;
    const int b = m0 >> 12, sp0 = m0 & 4095;
    const int wave = tid >> 6, lane = tid & 63;
    const int wn = wave * 32;                 // 8 waves x 32-col strips
    const int fm = lane & 15;
    const int fq = lane >> 4;

    // ---- phase A: ctx2 = ctx @ out_w^T + out_b  (K=256, BK=64) ----
    {
        f32x4 acc2[4][2] = {};
        for (int k0 = 0; k0 < 256; k0 += 64) {
            {   // ctx A-tile: 512 chunks, 1 round
                const int q = wave * 64 + lane;
                const int r = q >> 3;
                const int cs = (q & 7) ^ (r & 7);
                async_copy16(CTX + (size_t)(m0 + r) * 256 + k0 + cs * 8, &As[wave * 64 * 8]);
            }
            #pragma unroll
            for (int v = 0; v < 4; ++v) {   // out_w: 2048 chunks, 4 rounds
                const int qbu = v * 512 + wave * 64;
                const int q = qbu + lane;
                const int r = q >> 3;
                const int cs = (q & 7) ^ (r & 7);
                async_copy16(W2 + (size_t)r * 256 + k0 + cs * 8, &Bs[qbu * 8]);
            }
            __syncthreads();
            #pragma unroll
            for (int kk = 0; kk < 2; ++kk) {
                bf16x8 af[4], bw[2];
                #pragma unroll
                for (int i = 0; i < 4; ++i) {
                    const int row = i * 16 + fm;
                    af[i] = *(const bf16x8*)(&As[row * 64 + (((fq + kk * 4) ^ (fm & 7)) * 8)]);
                }
                #pragma unroll
                for (int j = 0; j < 2; ++j) {
                    const int row = wn + j * 16 + fm;
                    bw[j] = *(const bf16x8*)(&Bs[row * 64 + (((fq + kk * 4) ^ (fm & 7)) * 8)]);
                }
                #pragma unroll
                for (int i = 0; i < 4; ++i)
                    #pragma unroll
                    for (int j = 0; j < 2; ++j)
                        acc2[i][j] = __builtin_amdgcn_mfma_f32_16x16x32_bf16(af[i], bw[j], acc2[i][j], 0, 0, 0);
            }
            __syncthreads();
        }
        // park ctx2 in c2s (bf16), chunk j of row r at slot (j&24)|((j&7)^(r&7))
        #pragma unroll
        for (int j = 0; j < 2; ++j) {
            const int col = wn + j * 16 + fm;
            const float bv = out_b[col];
            const int jch = col >> 3, cl = col & 7;
            #pragma unroll
            for (int i = 0; i < 4; ++i)
                #pragma unroll
                for (int rr = 0; rr < 4; ++rr) {
                    const int row = i * 16 + fq * 4 + rr;
                    const int slot = (jch & 24) | ((jch & 7) ^ (row & 7));
                    c2s[row * 256 + slot * 8 + cl] = f2b(acc2[i][j][rr] + bv);
                }
        }
    }
    __syncthreads();

    // ---- phase B: y = [q | c2 | |q-c2| | q*c2] @ proj_w^T (K=1024, BK=64) ----
    f32x4 acc[4][2] = {};
    for (int k0 = 0; k0 < 1024; k0 += 64) {
        const int g = k0 >> 8;
        const int cb = k0 & 255;
        #pragma unroll
        for (int v = 0; v < 4; ++v) {       // proj_w: 2048 chunks, 4 rounds
            const int qbu = v * 512 + wave * 64;
            const int q = qbu + lane;
            const int r = q >> 3;
            const int cs = (q & 7) ^ (r & 7);
            async_copy16(W + (size_t)r * 1024 + k0 + cs * 8, &Bs[qbu * 8]);
        }
        if (g == 0) {
            const int q = wave * 64 + lane;
            const int r = q >> 3;
            const int cs = (q & 7) ^ (r & 7);
            async_copy16(X + (size_t)(m0 + r) * 256 + cb + cs * 8, &As[wave * 64 * 8]);
        } else if (g >= 2) {
            const int q = tid;              // 512 chunks, 1 round
            const int r = q >> 3;
            const int cs = (q & 7) ^ (r & 7);
            int4 qraw = *(const int4*)(X + (size_t)(m0 + r) * 256 + cb + cs * 8);
            const int jch = (cb >> 3) + cs;
            const int slot = (jch & 24) | ((jch & 7) ^ (r & 7));
            int4 craw = *(const int4*)(&c2s[r * 256 + slot * 8]);
            const short* qs = (const short*)&qraw;
            const short* cw = (const short*)&craw;
            short tmp[8];
            #pragma unroll
            for (int j = 0; j < 8; ++j) {
                const float qv = b2f(qs[j]), cv = b2f(cw[j]);
                tmp[j] = f2b(g == 2 ? fabsf(qv - cv) : qv * cv);
            }
            *(int4*)(&As[q * 8]) = *(int4*)tmp;
        }
        // g == 1: no A staging — frags read straight from c2s
        __syncthreads();
        #pragma unroll
        for (int kk = 0; kk < 2; ++kk) {
            bf16x8 af[4], bw[2];
            if (g == 1) {
                #pragma unroll
                for (int i = 0; i < 4; ++i) {
                    const int row = i * 16 + fm;
                    const int jch = (cb >> 3) + fq + kk * 4;
                    const int slot = (jch & 24) | ((jch & 7) ^ (row & 7));
                    af[i] = *(const bf16x8*)(&c2s[row * 256 + slot * 8]);
                }
            } else {
                #pragma unroll
                for (int i = 0; i < 4; ++i) {
                    const int row = i * 16 + fm;
                    af[i] = *(const bf16x8*)(&As[row * 64 + (((fq + kk * 4) ^ (fm & 7)) * 8)]);
                }
            }
            #pragma unroll
            for (int j = 0; j < 2; ++j) {
                const int row = wn + j * 16 + fm;
                bw[j] = *(const bf16x8*)(&Bs[row * 64 + (((fq + kk * 4) ^ (fm & 7)) * 8)]);
            }
            #pragma unroll
            for (int i = 0; i < 4; ++i)
                #pragma unroll
                for (int j = 0; j < 2; ++j)
                    acc[i][j] = __builtin_amdgcn_mfma_f32_16x16x32_bf16(af[i], bw[j], acc[i][j], 0, 0, 0);
        }
        __syncthreads();
    }
    // ---- epilogue: ys (bf16, stride 266) overlays c2s/As (dead); LN; ReLU; store ----
    short* ys = smem;
    #pragma unroll
    for (int j = 0; j < 2; ++j) {
        const int col = wn + j * 16 + fm;
        const float bv = bias[col];
        #pragma unroll
        for (int i = 0; i < 4; ++i)
            #pragma unroll
            for (int r = 0; r < 4; ++r)
                ys[(i * 16 + fq * 4 + r) * 266 + col] = f2b(acc[i][j][r] + bv);
    }
    __syncthreads();
    {   // stats: 8 threads per row, 64 rows
        const int tt = tid >> 3, seg = tid & 7;
        float s = 0.f, ss = 0.f;
        #pragma unroll
        for (int j = 0; j < 32; ++j) {
            const float v = b2f(ys[tt * 266 + seg * 32 + j]);
            s += v; ss += v * v;
        }
        s += __shfl_xor(s, 1, 64);  ss += __shfl_xor(ss, 1, 64);
        s += __shfl_xor(s, 2, 64);  ss += __shfl_xor(ss, 2, 64);
        s += __shfl_xor(s, 4, 64);  ss += __shfl_xor(ss, 4, 64);
        if (seg == 0) {
            const float mu = s * (1.f / 256.f);
            const float var = ss * (1.f / 256.f) - mu * mu;
            mu_s[tt] = mu;
            inv_s[tt] = rsqrtf(var + 1e-5f);
        }
    }
    __syncthreads();
    {   // normalize + relu + coalesced transposed store
        const int tl = tid & 63;
        const int j0 = tid >> 6;       // 0..7
        const float mu = mu_s[tl], inv = inv_s[tl];
        #pragma unroll
        for (int u = 0; u < 32; ++u) {
            const int j = j0 * 32 + u;
            const float v = (b2f(ys[tl * 266 + j]) - mu) * inv * ln_g[j] + ln_b[j];
            out[((size_t)(b * 256 + j) << 12) + sp0 + tl] = fmaxf(v, 0.f);
        }
    }
}

extern "C" void kernel_launch(void* const* d_in, const int* in_sizes, int n_in,
                              void* d_out, int out_size, void* d_ws, size_t ws_size,
                              hipStream_t stream) {
    (void)in_sizes; (void)n_in; (void)out_size; (void)ws_size;
    const float* feat   = (const float*)d_in[0];
    const float* in_w   = (const float*)d_in[1];
    const float* in_b   = (const float*)d_in[2];
    const float* out_w  = (const float*)d_in[3];
    const float* out_b  = (const float*)d_in[4];
    const float* proj_w = (const float*)d_in[5];
    const float* proj_b = (const float*)d_in[6];
    const float* ln_g   = (const float*)d_in[7];
    const float* ln_b   = (const float*)d_in[8];
    float* out = (float*)d_out;

    char* ws = (char*)d_ws;
    __hip_bfloat16* Xbf  = (__hip_bfloat16*)(ws);
    __hip_bfloat16* wbf  = (__hip_bfloat16*)(ws + (size_t)(16) * (1 << 20));
    __hip_bfloat16* qkv  = (__hip_bfloat16*)(ws + (size_t)(17) * (1 << 20));
    __hip_bfloat16* ctx  = (__hip_bfloat16*)(ws + (size_t)(65) * (1 << 20));
    __hip_bfloat16* in_wbf   = wbf;
    __hip_bfloat16* out_wbf  = wbf + 196608;
    __hip_bfloat16* proj_wbf = wbf + 262144;

    prep_kernel   <<<9216, 256, 0, stream>>>(feat, in_w, out_w, proj_w, Xbf, wbf);
    mfma_gemm<256, true><<<dim3(256, 6), 256, 0, stream>>>(Xbf, in_wbf, in_b, qkv, 768);
    attn_kernel   <<<NTOK / 4, 256, 0, stream>>>(qkv, ctx);
    proj_ln_fused <<<NTOK / 64, 512, 0, stream>>>(Xbf, ctx, out_wbf, out_b,
                                                  proj_wbf, proj_b, ln_g, ln_b, out);
}

// Round 13
// 181.345 us; speedup vs baseline: 1.0786x; 1.0278x over previous
//
#include <hip/hip_runtime.h>
#include <hip/hip_bf16.h>

// ContralateralAttention, round 12: r9 config (best measured: 185.7) + vectorized prep.
// ws layout (MB): Xbf [0,16) | wbf [16,17) | qkv [17,65) | ctx [65,81)

#define NTOK 32768

using bf16x8 = __attribute__((ext_vector_type(8))) short;
using f32x4  = __attribute__((ext_vector_type(4))) float;

__device__ __forceinline__ float b2f(short s) {
    unsigned u = ((unsigned)(unsigned short)s) << 16;
    union { unsigned u; float f; } c; c.u = u; return c.f;
}
__device__ __forceinline__ short f2b(float f) {
    __hip_bfloat16 h = __float2bfloat16(f);
    return *(short*)&h;
}
__device__ __forceinline__ void async_copy16(const void* g, void* l) {
    __builtin_amdgcn_global_load_lds(
        (const __attribute__((address_space(1))) unsigned int*)g,
        (__attribute__((address_space(3))) unsigned int*)l, 16, 0, 0);
}

// ---------------- prep: vectorized feat transpose+cast AND weight casts ----------------
// blocks [0,4096): 64tok x 32ch transpose tiles (float4 loads, short4 stores).
// blocks [4096,4352): weight casts, float4 -> short4.
__global__ __launch_bounds__(256) void prep_kernel(const float* __restrict__ feat,
                                                   const float* __restrict__ in_w,
                                                   const float* __restrict__ out_w,
                                                   const float* __restrict__ proj_w,
                                                   __hip_bfloat16* __restrict__ X,
                                                   __hip_bfloat16* __restrict__ wbf) {
    const int bid = blockIdx.x;
    const int tid = threadIdx.x;
    if (bid < 4096) {
        __shared__ float tile[32][68];
        const int b   = bid >> 9;
        const int rem = bid & 511;
        const int sp0 = (rem & 63) * 64;
        const int c0  = (rem >> 6) * 32;
        #pragma unroll
        for (int u = 0; u < 2; ++u) {
            const int idx = tid + u * 256;      // 0..511
            const int cl = idx >> 4;            // 0..31
            const int sq = (idx & 15) * 4;      // 0..60
            const float4 v = *(const float4*)(feat + ((size_t)(b * 256 + c0 + cl) << 12) + sp0 + sq);
            tile[cl][sq]     = v.x;
            tile[cl][sq + 1] = v.y;
            tile[cl][sq + 2] = v.z;
            tile[cl][sq + 3] = v.w;
        }
        __syncthreads();
        #pragma unroll
        for (int u = 0; u < 2; ++u) {
            const int idx = tid + u * 256;      // 0..511
            const int tok = idx >> 3;           // 0..63
            const int cq  = (idx & 7) * 4;      // 0..28
            short4 s;
            s.x = f2b(tile[cq][tok]);
            s.y = f2b(tile[cq + 1][tok]);
            s.z = f2b(tile[cq + 2][tok]);
            s.w = f2b(tile[cq + 3][tok]);
            *(short4*)(X + (size_t)(b * 4096 + sp0 + tok) * 256 + c0 + cq) = s;
        }
    } else {
        const int i4 = (bid - 4096) * 1024 + tid * 4;
        if (i4 < 196608) {
            const float4 v = *(const float4*)(in_w + i4);
            short4 s = {f2b(v.x), f2b(v.y), f2b(v.z), f2b(v.w)};
            *(short4*)(wbf + i4) = s;
        }
        if (i4 < 65536) {
            const float4 v = *(const float4*)(out_w + i4);
            short4 s = {f2b(v.x), f2b(v.y), f2b(v.z), f2b(v.w)};
            *(short4*)(wbf + 196608 + i4) = s;
        }
        if (i4 < 262144) {
            const float4 v = *(const float4*)(proj_w + i4);
            short4 s = {f2b(v.x), f2b(v.y), f2b(v.z), f2b(v.w)};
            *(short4*)(wbf + 262144 + i4) = s;
        }
    }
}

// ---------------- MFMA GEMM (qkv): 256 thr, M=128 x N=128, BK=64, DMA staging ----------------
template <int KDIM, bool OUT_BF16>
__global__ __launch_bounds__(256) void mfma_gemm(const __hip_bfloat16* __restrict__ A,
                                                 const __hip_bfloat16* __restrict__ W,
                                                 const float* __restrict__ bias,
                                                 void* __restrict__ C, int Ntot) {
    __shared__ __align__(16) short As[128 * 64];
    __shared__ __align__(16) short Bs[128 * 64];
    const int tid = threadIdx.x;
    const int m0 = blockIdx.x * 128;
    const int n0 = blockIdx.y * 128;
    const int wave = tid >> 6, lane = tid & 63;
    const int wm = (wave >> 1) * 64;
    const int wn = (wave & 1) * 64;
    const int fm = lane & 15;
    const int fq = lane >> 4;

    f32x4 acc[4][4] = {};

    for (int k0 = 0; k0 < KDIM; k0 += 64) {
        #pragma unroll
        for (int v = 0; v < 4; ++v) {
            const int qb = v * 256 + wave * 64;
            const int q = qb + lane;
            const int r = q >> 3;
            const int cs = (q & 7) ^ (r & 7);
            async_copy16(A + (size_t)(m0 + r) * KDIM + k0 + cs * 8, &As[qb * 8]);
            async_copy16(W + (size_t)(n0 + r) * KDIM + k0 + cs * 8, &Bs[qb * 8]);
        }
        __syncthreads();
        #pragma unroll
        for (int kk = 0; kk < 2; ++kk) {
            bf16x8 af[4], bw[4];
            #pragma unroll
            for (int i = 0; i < 4; ++i) {
                const int row = wm + i * 16 + fm;
                af[i] = *(const bf16x8*)(&As[row * 64 + (((fq + kk * 4) ^ (fm & 7)) * 8)]);
            }
            #pragma unroll
            for (int j = 0; j < 4; ++j) {
                const int row = wn + j * 16 + fm;
                bw[j] = *(const bf16x8*)(&Bs[row * 64 + (((fq + kk * 4) ^ (fm & 7)) * 8)]);
            }
            #pragma unroll
            for (int i = 0; i < 4; ++i)
                #pragma unroll
                for (int j = 0; j < 4; ++j)
                    acc[i][j] = __builtin_amdgcn_mfma_f32_16x16x32_bf16(af[i], bw[j], acc[i][j], 0, 0, 0);
        }
        __syncthreads();
    }
    #pragma unroll
    for (int j = 0; j < 4; ++j) {
        const int col = n0 + wn + j * 16 + fm;
        const float bv = bias[col];
        #pragma unroll
        for (int i = 0; i < 4; ++i) {
            #pragma unroll
            for (int r = 0; r < 4; ++r) {
                const int row = m0 + wm + i * 16 + fq * 4 + r;
                const float v = acc[i][j][r] + bv;
                if (OUT_BF16)
                    ((__hip_bfloat16*)C)[(size_t)row * Ntot + col] = __float2bfloat16(v);
                else
                    ((float*)C)[(size_t)row * Ntot + col] = v;
            }
        }
    }
}

// ---------------- sparse attention (r7 form, validated) ----------------
#define P0DY ((2u)|(2u<<3)|(2u<<6)|(2u<<9)|(2u<<12)|(1u<<15)|(1u<<18)|(1u<<21))
#define P0DX ((2u)|(1u<<3)|(3u<<6)|(0u<<9)|(4u<<12)|(2u<<15)|(1u<<18)|(3u<<21))
#define P1DY ((3u)|(3u<<3)|(3u<<6)|(0u<<9)|(4u<<12)|(2u<<15)|(2u<<18)|(2u<<21))
#define P1DX ((2u)|(1u<<3)|(3u<<6)|(2u<<9)|(2u<<12)|(2u<<15)|(2u<<18)|(2u<<21))

__global__ __launch_bounds__(256) void attn_kernel(const __hip_bfloat16* __restrict__ qkv,
                                                   __hip_bfloat16* __restrict__ ctx) {
    const int t = blockIdx.x * 4 + (threadIdx.x >> 6);
    const int lane = threadIdx.x & 63;
    const int n  = lane >> 3;
    const int cg = lane & 7;
    const int x6 = t & 63;
    const int yq = (t >> 6) & 63;
    const int b  = t >> 12;
    const int side = x6 >> 5;
    const int x = x6 & 31;

    bool valid[2];
    size_t kb[2];
    #pragma unroll
    for (int p = 0; p < 2; ++p) {
        const unsigned dyp = p ? P1DY : P0DY;
        const unsigned dxp = p ? P1DX : P0DX;
        const int sh = 3 * n;
        const int dy = (int)((dyp >> sh) & 7) - 2;
        const int dx = (int)((dxp >> sh) & 7) - 2;
        const int yy = yq + dy, xx = x + dx;
        valid[p] = (p == 0 || n < 5) && yy >= 0 && yy < 64 && xx >= 0 && xx < 32;
        const int xm = side ? (31 - xx) : (63 - xx);
        int tm = (b << 12) + (yy << 6) + xm;
        if (!valid[p]) tm = t;
        kb[p] = (size_t)tm * 768 + 256 + cg * 8;
    }
    const size_t qb = (size_t)t * 768 + cg * 8;
    const size_t ob = (size_t)t * 256;

    #pragma unroll
    for (int hp = 0; hp < 2; ++hp) {
        bf16x8 q8[2], k8[2][2], v8[2][2];
        #pragma unroll
        for (int hh = 0; hh < 2; ++hh) {
            const int h = hp * 2 + hh;
            q8[hh] = *(const bf16x8*)(qkv + qb + h * 64);
            #pragma unroll
            for (int p = 0; p < 2; ++p) {
                k8[hh][p] = *(const bf16x8*)(qkv + kb[p] + h * 64);
                v8[hh][p] = *(const bf16x8*)(qkv + kb[p] + h * 64 + 256);
            }
        }
        #pragma unroll
        for (int hh = 0; hh < 2; ++hh) {
            float sc[2];
            #pragma unroll
            for (int p = 0; p < 2; ++p) {
                float s = 0.f;
                #pragma unroll
                for (int j = 0; j < 8; ++j) s += b2f(q8[hh][j]) * b2f(k8[hh][p][j]);
                s += __shfl_xor(s, 1, 64);
                s += __shfl_xor(s, 2, 64);
                s += __shfl_xor(s, 4, 64);
                sc[p] = valid[p] ? s * 0.125f : -1e30f;
            }
            const float p0 = __expf(sc[0]);
            const float p1 = __expf(sc[1]);
            float l = p0 + p1;
            l += __shfl_xor(l, 8, 64);
            l += __shfl_xor(l, 16, 64);
            l += __shfl_xor(l, 32, 64);

            float o[8];
            #pragma unroll
            for (int j = 0; j < 8; ++j)
                o[j] = p0 * b2f(v8[hh][0][j]) + p1 * b2f(v8[hh][1][j]);
            float r4[4];
            #pragma unroll
            for (int i = 0; i < 4; ++i) {
                const float a = o[2 * i], bb = o[2 * i + 1];
                const float mine = (n & 1) ? bb : a;
                const float theirs = (n & 1) ? a : bb;
                r4[i] = mine + __shfl_xor(theirs, 8, 64);
            }
            float r2[2];
            #pragma unroll
            for (int i = 0; i < 2; ++i) {
                const float a = r4[2 * i], bb = r4[2 * i + 1];
                const float mine = (n & 2) ? bb : a;
                const float theirs = (n & 2) ? a : bb;
                r2[i] = mine + __shfl_xor(theirs, 16, 64);
            }
            float ov;
            {
                const float a = r2[0], bb = r2[1];
                const float mine = (n & 4) ? bb : a;
                const float theirs = (n & 4) ? a : bb;
                ov = mine + __shfl_xor(theirs, 32, 64);
            }
            const float rl = __builtin_amdgcn_rcpf(l);
            ctx[ob + (hp * 2 + hh) * 64 + cg * 8 + n] = __float2bfloat16(ov * rl);
        }
    }
}

// ---------------- fused: ctx2 = ctx@out_w^T+out_b (in LDS), then proj+LN+ReLU+store ----------------
// r9 configuration (best measured): 256 thr, M=64, BK=64, LDS 72KB.
__global__ __launch_bounds__(256) void proj_ln_fused(const __hip_bfloat16* __restrict__ X,
                                                     const __hip_bfloat16* __restrict__ CTX,
                                                     const __hip_bfloat16* __restrict__ W2,
                                                     const float* __restrict__ out_b,
                                                     const __hip_bfloat16* __restrict__ W,
                                                     const float* __restrict__ bias,
                                                     const float* __restrict__ ln_g,
                                                     const float* __restrict__ ln_b,
                                                     float* __restrict__ out) {
    __shared__ __align__(16) short smem[36864];   // 72 KB
    __shared__ float mu_s[64], inv_s[64];
    short* c2s = smem;            // 64 x 256 (32 KB), persists through phase B
    short* As  = smem + 16384;    // 64 x 64 staging (8 KB)
    short* Bs  = smem + 20480;    // 256 x 64 staging (32 KB)
    const int tid = threadIdx.x;
    const int m0 = blockIdx.x * 64;
    const int b = m0 >> 12, sp0 = m0 & 4095;
    const int wave = tid >> 6, lane = tid & 63;
    const int wn = wave * 64;
    const int fm = lane & 15;
    const int fq = lane >> 4;

    // ---- phase A: ctx2 tile ----
    {
        f32x4 acc2[4][4] = {};
        for (int k0 = 0; k0 < 256; k0 += 64) {
            #pragma unroll
            for (int v = 0; v < 2; ++v) {          // ctx: 512 chunks
                const int qbu = v * 256 + wave * 64;
                const int q = qbu + lane;
                const int r = q >> 3;
                const int cs = (q & 7) ^ (r & 7);
                async_copy16(CTX + (size_t)(m0 + r) * 256 + k0 + cs * 8, &As[qbu * 8]);
            }
            #pragma unroll
            for (int v = 0; v < 8; ++v) {          // out_w: 2048 chunks
                const int qbu = v * 256 + wave * 64;
                const int q = qbu + lane;
                const int r = q >> 3;
                const int cs = (q & 7) ^ (r & 7);
                async_copy16(W2 + (size_t)r * 256 + k0 + cs * 8, &Bs[qbu * 8]);
            }
            __syncthreads();
            #pragma unroll
            for (int kk = 0; kk < 2; ++kk) {
                bf16x8 af[4], bw[4];
                #pragma unroll
                for (int i = 0; i < 4; ++i) {
                    const int row = i * 16 + fm;
                    af[i] = *(const bf16x8*)(&As[row * 64 + (((fq + kk * 4) ^ (fm & 7)) * 8)]);
                }
                #pragma unroll
                for (int j = 0; j < 4; ++j) {
                    const int row = wn + j * 16 + fm;
                    bw[j] = *(const bf16x8*)(&Bs[row * 64 + (((fq + kk * 4) ^ (fm & 7)) * 8)]);
                }
                #pragma unroll
                for (int i = 0; i < 4; ++i)
                    #pragma unroll
                    for (int j = 0; j < 4; ++j)
                        acc2[i][j] = __builtin_amdgcn_mfma_f32_16x16x32_bf16(af[i], bw[j], acc2[i][j], 0, 0, 0);
            }
            __syncthreads();
        }
        #pragma unroll
        for (int j = 0; j < 4; ++j) {
            const int col = wn + j * 16 + fm;
            const float bv = out_b[col];
            const int jch = col >> 3, cl = col & 7;
            #pragma unroll
            for (int i = 0; i < 4; ++i)
                #pragma unroll
                for (int rr = 0; rr < 4; ++rr) {
                    const int row = i * 16 + fq * 4 + rr;
                    const int slot = (jch & 24) | ((jch & 7) ^ (row & 7));
                    c2s[row * 256 + slot * 8 + cl] = f2b(acc2[i][j][rr] + bv);
                }
        }
    }
    __syncthreads();

    // ---- phase B: proj GEMM over K=1024 groups [q | c2 | |q-c2| | q*c2] ----
    f32x4 acc[4][4] = {};
    for (int k0 = 0; k0 < 1024; k0 += 64) {
        const int g = k0 >> 8;
        const int cb = k0 & 255;
        #pragma unroll
        for (int v = 0; v < 8; ++v) {              // proj_w: 2048 chunks
            const int qbu = v * 256 + wave * 64;
            const int q = qbu + lane;
            const int r = q >> 3;
            const int cs = (q & 7) ^ (r & 7);
            async_copy16(W + (size_t)r * 1024 + k0 + cs * 8, &Bs[qbu * 8]);
        }
        if (g == 0) {
            #pragma unroll
            for (int v = 0; v < 2; ++v) {
                const int qbu = v * 256 + wave * 64;
                const int q = qbu + lane;
                const int r = q >> 3;
                const int cs = (q & 7) ^ (r & 7);
                async_copy16(X + (size_t)(m0 + r) * 256 + cb + cs * 8, &As[qbu * 8]);
            }
        } else if (g >= 2) {
            #pragma unroll
            for (int v = 0; v < 2; ++v) {
                const int q = v * 256 + tid;
                const int r = q >> 3;
                const int cs = (q & 7) ^ (r & 7);
                int4 qraw = *(const int4*)(X + (size_t)(m0 + r) * 256 + cb + cs * 8);
                const int jch = (cb >> 3) + cs;
                const int slot = (jch & 24) | ((jch & 7) ^ (r & 7));
                int4 craw = *(const int4*)(&c2s[r * 256 + slot * 8]);
                const short* qs = (const short*)&qraw;
                const short* cw = (const short*)&craw;
                short tmp[8];
                #pragma unroll
                for (int j = 0; j < 8; ++j) {
                    const float qv = b2f(qs[j]), cv = b2f(cw[j]);
                    tmp[j] = f2b(g == 2 ? fabsf(qv - cv) : qv * cv);
                }
                *(int4*)(&As[q * 8]) = *(int4*)tmp;
            }
        }
        // g == 1: no A staging — frags read straight from c2s
        __syncthreads();
        #pragma unroll
        for (int kk = 0; kk < 2; ++kk) {
            bf16x8 af[4], bw[4];
            if (g == 1) {
                #pragma unroll
                for (int i = 0; i < 4; ++i) {
                    const int row = i * 16 + fm;
                    const int jch = (cb >> 3) + fq + kk * 4;
                    const int slot = (jch & 24) | ((jch & 7) ^ (row & 7));
                    af[i] = *(const bf16x8*)(&c2s[row * 256 + slot * 8]);
                }
            } else {
                #pragma unroll
                for (int i = 0; i < 4; ++i) {
                    const int row = i * 16 + fm;
                    af[i] = *(const bf16x8*)(&As[row * 64 + (((fq + kk * 4) ^ (fm & 7)) * 8)]);
                }
            }
            #pragma unroll
            for (int j = 0; j < 4; ++j) {
                const int row = wn + j * 16 + fm;
                bw[j] = *(const bf16x8*)(&Bs[row * 64 + (((fq + kk * 4) ^ (fm & 7)) * 8)]);
            }
            #pragma unroll
            for (int i = 0; i < 4; ++i)
                #pragma unroll
                for (int j = 0; j < 4; ++j)
                    acc[i][j] = __builtin_amdgcn_mfma_f32_16x16x32_bf16(af[i], bw[j], acc[i][j], 0, 0, 0);
        }
        __syncthreads();
    }
    // ---- epilogue: ys (bf16, stride 266) overlays c2s/As (dead); LN; ReLU; store ----
    short* ys = smem;
    #pragma unroll
    for (int j = 0; j < 4; ++j) {
        const int col = wn + j * 16 + fm;
        const float bv = bias[col];
        #pragma unroll
        for (int i = 0; i < 4; ++i)
            #pragma unroll
            for (int r = 0; r < 4; ++r)
                ys[(i * 16 + fq * 4 + r) * 266 + col] = f2b(acc[i][j][r] + bv);
    }
    __syncthreads();
    {
        const int tt = tid >> 2, seg = tid & 3;
        float s = 0.f, ss = 0.f;
        #pragma unroll
        for (int j = 0; j < 64; ++j) {
            const float v = b2f(ys[tt * 266 + seg * 64 + j]);
            s += v; ss += v * v;
        }
        s += __shfl_xor(s, 1, 64);  ss += __shfl_xor(ss, 1, 64);
        s += __shfl_xor(s, 2, 64);  ss += __shfl_xor(ss, 2, 64);
        if (seg == 0) {
            const float mu = s * (1.f / 256.f);
            const float var = ss * (1.f / 256.f) - mu * mu;
            mu_s[tt] = mu;
            inv_s[tt] = rsqrtf(var + 1e-5f);
        }
    }
    __syncthreads();
    {
        const int tl = tid & 63;
        const int j0 = tid >> 6;
        const float mu = mu_s[tl], inv = inv_s[tl];
        #pragma unroll
        for (int u = 0; u < 64; ++u) {
            const int j = j0 * 64 + u;
            const float v = (b2f(ys[tl * 266 + j]) - mu) * inv * ln_g[j] + ln_b[j];
            out[((size_t)(b * 256 + j) << 12) + sp0 + tl] = fmaxf(v, 0.f);
        }
    }
}

extern "C" void kernel_launch(void* const* d_in, const int* in_sizes, int n_in,
                              void* d_out, int out_size, void* d_ws, size_t ws_size,
                              hipStream_t stream) {
    (void)in_sizes; (void)n_in; (void)out_size; (void)ws_size;
    const float* feat   = (const float*)d_in[0];
    const float* in_w   = (const float*)d_in[1];
    const float* in_b   = (const float*)d_in[2];
    const float* out_w  = (const float*)d_in[3];
    const float* out_b  = (const float*)d_in[4];
    const float* proj_w = (const float*)d_in[5];
    const float* proj_b = (const float*)d_in[6];
    const float* ln_g   = (const float*)d_in[7];
    const float* ln_b   = (const float*)d_in[8];
    float* out = (float*)d_out;

    char* ws = (char*)d_ws;
    __hip_bfloat16* Xbf  = (__hip_bfloat16*)(ws);
    __hip_bfloat16* wbf  = (__hip_bfloat16*)(ws + (size_t)(16) * (1 << 20));
    __hip_bfloat16* qkv  = (__hip_bfloat16*)(ws + (size_t)(17) * (1 << 20));
    __hip_bfloat16* ctx  = (__hip_bfloat16*)(ws + (size_t)(65) * (1 << 20));
    __hip_bfloat16* in_wbf   = wbf;
    __hip_bfloat16* out_wbf  = wbf + 196608;
    __hip_bfloat16* proj_wbf = wbf + 262144;

    prep_kernel   <<<4352, 256, 0, stream>>>(feat, in_w, out_w, proj_w, Xbf, wbf);
    mfma_gemm<256, true><<<dim3(256, 6), 256, 0, stream>>>(Xbf, in_wbf, in_b, qkv, 768);
    attn_kernel   <<<NTOK / 4, 256, 0, stream>>>(qkv, ctx);
    proj_ln_fused <<<NTOK / 64, 256, 0, stream>>>(Xbf, ctx, out_wbf, out_b,
                                                  proj_wbf, proj_b, ln_g, ln_b, out);
}